// Round 9
// baseline (431.038 us; speedup 1.0000x reference)
//
#include <hip/hip_runtime.h>
#include <math.h>

#define NA 10000
#define NE 250000
#define FD 128
#define NRBF 20
#define RCUT 5.0f

typedef _Float16 h16;
typedef __attribute__((ext_vector_type(8))) _Float16 half8;
typedef __attribute__((ext_vector_type(2))) _Float16 half2v;
typedef __attribute__((ext_vector_type(4))) float f32x4;

static __device__ __forceinline__ half8 f32x8_to_h8(const float* p) {
    float4 a = *(const float4*)p;
    float4 b = *(const float4*)(p + 4);
    half8 r;
    r[0] = (h16)a.x; r[1] = (h16)a.y; r[2] = (h16)a.z; r[3] = (h16)a.w;
    r[4] = (h16)b.x; r[5] = (h16)b.y; r[6] = (h16)b.z; r[7] = (h16)b.w;
    return r;
}
static __device__ __forceinline__ float silu(float v) {
    return v / (1.f + expf(-v));
}

// ====== mega setup: geom | csr | weights | q-init ======
// ed[e] = one 64B row: 20 gauss*fcut, fcut, 0,0,0 (h16) + float4 dir.
// zs[e] = Z[idx_j[e]] (ushort) — the iteration-0 gather index stream.
__global__ __launch_bounds__(256) void setup_kernel(
    const float* __restrict__ R, const int* __restrict__ idx_i,
    const int* __restrict__ idx_j, const float* __restrict__ offsets,
    const int* __restrict__ Zt, const float* __restrict__ emb, float* __restrict__ q,
    h16* __restrict__ ed, unsigned short* __restrict__ zs, int* __restrict__ row_start,
    const float* __restrict__ int_W1, const float* __restrict__ int_W2,
    const float* __restrict__ mix_Wmu, const float* __restrict__ mix_W1,
    const float* __restrict__ mix_W2,
    h16* __restrict__ W1t, h16* __restrict__ W2t, h16* __restrict__ WmuT,
    h16* __restrict__ mW1t, h16* __restrict__ mW2t,
    const float* __restrict__ filt_W, const float* __restrict__ filt_b,
    h16* __restrict__ fwt)
{
    const int b = blockIdx.x;
    if (b < 977) {
        int e = b * 256 + threadIdx.x;
        if (e >= NE) return;
        int i = idx_i[e], j = idx_j[e];
        float rx = R[j * 3 + 0] - R[i * 3 + 0] + offsets[e * 3 + 0];
        float ry = R[j * 3 + 1] - R[i * 3 + 1] + offsets[e * 3 + 1];
        float rz = R[j * 3 + 2] - R[i * 3 + 2] + offsets[e * 3 + 2];
        float d = sqrtf(rx * rx + ry * ry + rz * rz);
        float inv = 1.f / d;
        float fcut = 0.f;
        if (d < RCUT) fcut = 0.5f * (cosf(d * (3.14159265358979323846f / RCUT)) + 1.f);
        h16* pp = ed + (size_t)e * 32;
        const float delta = RCUT / 19.f;
        const float coeff = -0.5f / (delta * delta);
#pragma unroll
        for (int r = 0; r < NRBF; ++r) {
            float dc = d - (float)r * delta;
            pp[r] = (h16)(expf(coeff * dc * dc) * fcut);
        }
        pp[20] = (h16)fcut;
        pp[21] = (h16)0.f; pp[22] = (h16)0.f; pp[23] = (h16)0.f;
        *(float4*)(pp + 24) = make_float4(rx * inv, ry * inv, rz * inv, 0.f);
        zs[e] = (unsigned short)Zt[j];
    } else if (b < 1017) {
        int n = (b - 977) * 256 + threadIdx.x;
        if (n > NA) return;
        int lo = 0, hi = NE;
        while (lo < hi) {
            int mid = (lo + hi) >> 1;
            if (idx_i[mid] < n) lo = mid + 1; else hi = mid;
        }
        row_start[n] = lo;
    } else if (b < 3177) {
        int idx = (b - 1017) * 256 + threadIdx.x;
        if (idx < 49152) {                       // int_W1: K=128,N=128
            int bt = idx >> 14, rem = idx & 16383;
            int nn = rem >> 7, kk = rem & 127;
            W1t[idx] = (h16)int_W1[(size_t)bt * 16384 + kk * 128 + nn];
        } else if ((idx -= 49152) < 147456) {    // int_W2: K=128,N=384
            int bt = idx / 49152, rem = idx - bt * 49152;
            int nn = rem >> 7, kk = rem & 127;
            W2t[idx] = (h16)int_W2[(size_t)bt * 49152 + kk * 384 + nn];
        } else if ((idx -= 147456) < 98304) {    // mix_Wmu: K=128,N=256
            int bt = idx >> 15, rem = idx & 32767;
            int nn = rem >> 7, kk = rem & 127;
            WmuT[idx] = (h16)mix_Wmu[(size_t)bt * 32768 + kk * 256 + nn];
        } else if ((idx -= 98304) < 98304) {     // mix_W1: K=256,N=128
            int bt = idx >> 15, rem = idx & 32767;
            int nn = rem >> 8, kk = rem & 255;
            mW1t[idx] = (h16)mix_W1[(size_t)bt * 32768 + kk * 128 + nn];
        } else if ((idx -= 98304) < 147456) {    // mix_W2: K=128,N=384
            int bt = idx / 49152, rem = idx - bt * 49152;
            int nn = rem >> 7, kk = rem & 127;
            mW2t[idx] = (h16)mix_W2[(size_t)bt * 49152 + kk * 384 + nn];
        } else if ((idx -= 147456) < 12288) {    // fwt [384][32]
            int nn = idx >> 5, kk = idx & 31;
            float v = 0.f;
            if (kk < 20) v = filt_W[kk * 384 + nn];
            else if (kk == 20) v = filt_b[nn];
            fwt[idx] = (h16)v;
        }
    } else {
        // q-init: q[n] = emb[Z[n]] (16 atoms / block, coalesced float4 pairs)
        int a = (b - 3177) * 16 + (threadIdx.x >> 4);
        int f0 = (threadIdx.x & 15) * 8;
        if (a < NA) {
            const float* src = emb + (size_t)Zt[a] * 128 + f0;
            float4 v0 = *(const float4*)src;
            float4 v1 = *(const float4*)(src + 4);
            *(float4*)&q[(size_t)a * 128 + f0] = v0;
            *(float4*)&q[(size_t)a * 128 + f0 + 4] = v1;
        }
    }
}

// ====== iteration-0 interaction MLP, Z-DEDUPED (proven r8: bit-identical) ==
__global__ __launch_bounds__(256) void intmlp0z_kernel(
    const float* __restrict__ emb,
    const h16* __restrict__ W1t, const float* __restrict__ b1,
    const h16* __restrict__ W2t, const float* __restrict__ b2, h16* __restrict__ x01z)
{
    __shared__ h16 Hs[16 * 136];
    const int tid = threadIdx.x;
    const int wave = tid >> 6, lane = tid & 63;
    const int ar = lane & 15, kg = lane >> 4;
    const int row0 = blockIdx.x * 16;

    const int zr = min(row0 + ar, 100);
    f32x4 a1[2] = {};
    for (int ks = 0; ks < 128; ks += 32) {
        int k = ks + kg * 8;
        half8 af = f32x8_to_h8(emb + (size_t)zr * 128 + k);
#pragma unroll
        for (int tt = 0; tt < 2; ++tt) {
            int t = wave * 2 + tt;
            half8 bf = *(const half8*)&W1t[(size_t)(t * 16 + ar) * 128 + k];
            a1[tt] = __builtin_amdgcn_mfma_f32_16x16x32_f16(af, bf, a1[tt], 0, 0, 0);
        }
    }
#pragma unroll
    for (int tt = 0; tt < 2; ++tt) {
        int col = (wave * 2 + tt) * 16 + ar;
        float bb = b1[col];
#pragma unroll
        for (int r = 0; r < 4; ++r)
            Hs[(kg * 4 + r) * 136 + col] = (h16)silu(a1[tt][r] + bb);
    }
    __syncthreads();
    f32x4 a2[6] = {};
    for (int ks = 0; ks < 128; ks += 32) {
        int k = ks + kg * 8;
        half8 af = *(const half8*)&Hs[ar * 136 + k];
#pragma unroll
        for (int tt = 0; tt < 6; ++tt) {
            int t = wave * 6 + tt;
            half8 bf = *(const half8*)&W2t[(size_t)(t * 16 + ar) * 128 + k];
            a2[tt] = __builtin_amdgcn_mfma_f32_16x16x32_f16(af, bf, a2[tt], 0, 0, 0);
        }
    }
#pragma unroll
    for (int tt = 0; tt < 6; ++tt) {
        int col = (wave * 6 + tt) * 16 + ar;
        if (col < 256) {                         // x2 (col>=256) unused at iter 0
            float bb = b2[col];
            int slot = col >> 7, ff = col & 127;
#pragma unroll
            for (int r = 0; r < 4; ++r) {
                int z = row0 + kg * 4 + r;
                if (z <= 100)
                    x01z[((size_t)z * 128 + ff) * 2 + slot] = (h16)(a2[tt][r] + bb);
            }
        }
    }
}

// ====== edge kernel: round-2 proven body + index-FIFO depth 2 ======
// The ONLY change vs the 73.5-76.5us equilibrium: the gather index for e+1
// is read from a 2-deep register FIFO (loaded 2 iterations earlier, so it
// has ARRIVED), instead of `j2 = idx[ep]; gather(j2)` back-to-back in the
// same iteration. This removes ~150-200cy of idx-load latency from the
// per-edge dependent chain. Same 8 VMEM/iteration, +1 int register, no
// barriers, compute body byte-identical.
template<bool HAS_MU>
__global__ __launch_bounds__(128, 4) void edge_kernel(
    const h16* __restrict__ ed, const h16* __restrict__ fwt,
    const int* __restrict__ row_start, const int* __restrict__ idx_j,
    const unsigned short* __restrict__ zs,
    const h16* __restrict__ gat, const float* __restrict__ mup,
    float* __restrict__ mun, h16* __restrict__ mu16n, float* __restrict__ q)
{
    const int n = blockIdx.x, f = threadIdx.x;
    half8 FA[3], FB[3], FC[3];
    {
        const half8* pa = (const half8*)(fwt + (size_t)f * 32);
        const half8* pb = (const half8*)(fwt + (size_t)(128 + f) * 32);
#pragma unroll
        for (int r = 0; r < 3; ++r) { FA[r] = pa[r]; FB[r] = pb[r]; }
        if (HAS_MU) {
            const half8* pc = (const half8*)(fwt + (size_t)(256 + f) * 32);
#pragma unroll
            for (int r = 0; r < 3; ++r) FC[r] = pc[r];
        }
    }
    asm volatile("" : "+v"(FA[0]), "+v"(FA[1]), "+v"(FA[2]),
                      "+v"(FB[0]), "+v"(FB[1]), "+v"(FB[2]));
    if (HAS_MU)
        asm volatile("" : "+v"(FC[0]), "+v"(FC[1]), "+v"(FC[2]));

    half2v fa[12], fb[12], fc[12];
    *(half8*)&fa[0] = FA[0]; *(half8*)&fa[4] = FA[1]; *(half8*)&fa[8] = FA[2];
    *(half8*)&fb[0] = FB[0]; *(half8*)&fb[4] = FB[1]; *(half8*)&fb[8] = FB[2];
    if (HAS_MU) {
        *(half8*)&fc[0] = FC[0]; *(half8*)&fc[4] = FC[1]; *(half8*)&fc[8] = FC[2];
    }

    const size_t rstr = HAS_MU ? 768 : 256;      // h16 units per gather row
    const h16* xmf = gat + (HAS_MU ? (size_t)f * 6 : (size_t)f * 2);
    float accq = 0.f, am0 = 0.f, am1 = 0.f, am2 = 0.f;
    const int e0 = row_start[n], e1 = row_start[n + 1];

#define LD_IDX(E) (HAS_MU ? idx_j[E] : (int)zs[E])

    if (e0 < e1) {
        const int elast = e1 - 1;
        // prologue: gather for e0 (blocking — once per atom), FIFO for e0+1/e0+2
        int j0 = LD_IDX(e0);
        const unsigned* gp = (const unsigned*)(xmf + (size_t)j0 * rstr);
        unsigned g0n = gp[0], g1n = 0u, g2n = 0u;
        if (HAS_MU) { g1n = gp[1]; g2n = gp[2]; }
        int eA = (e0 + 1 < elast) ? e0 + 1 : elast;
        int eB = (e0 + 2 < elast) ? e0 + 2 : elast;
        int jA = LD_IDX(eA);
        int jB = LD_IDX(eB);
        // ed row prologue (edge e0)
        const h16* pb8 = ed + (size_t)e0 * 32;
        half8 p0n = *(const half8*)pb8;
        half8 p1n = *(const half8*)(pb8 + 8);
        half8 p2n = *(const half8*)(pb8 + 16);
        float4 dn = *(const float4*)(pb8 + 24);
        for (int e = e0; e < e1; ++e) {
            unsigned g0 = g0n, g1 = g1n, g2 = g2n;
            half8 p0 = p0n, p1 = p1n, p2 = p2n;
            float4 g = dn;
            // issue gather for e+1 with jA (arrived: loaded 2 iterations ago)
            const unsigned* gp2 = (const unsigned*)(xmf + (size_t)jA * rstr);
            g0n = gp2[0];
            if (HAS_MU) { g1n = gp2[1]; g2n = gp2[2]; }
            // rotate FIFO, issue idx load for e+3 (clamped)
            jA = jB;
            int e3 = (e + 3 < elast) ? e + 3 : elast;
            jB = LD_IDX(e3);
            // issue ed row for e+1 (clamped)
            int ep = (e + 1 < e1) ? e + 1 : e;
            const h16* pb2 = ed + (size_t)ep * 32;
            p0n = *(const half8*)pb2;
            p1n = *(const half8*)(pb2 + 8);
            p2n = *(const half8*)(pb2 + 16);
            dn = *(const float4*)(pb2 + 24);
            // ---- compute on current edge (round-2 body, do not touch) ----
            half2v pr[12];
            *(half8*)&pr[0] = p0; *(half8*)&pr[4] = p1; *(half8*)&pr[8] = p2;
            half2v A0 = {(h16)0.f, (h16)0.f}, A1 = A0, A2 = A0;
#pragma unroll
            for (int r = 0; r < 11; ++r) {
                A0 = pr[r] * fa[r] + A0;
                A1 = pr[r] * fb[r] + A1;
                if (HAS_MU) A2 = pr[r] * fc[r] + A2;
            }
            float w0 = (float)A0[0] + (float)A0[1];
            float w1 = (float)A1[0] + (float)A1[1];
            half2v h01 = __builtin_bit_cast(half2v, g0);
            half2v h23 = __builtin_bit_cast(half2v, g1);
            float x0 = (float)h01[0], x1 = (float)h01[1];
            accq = fmaf(w0, x0, accq);
            float xw1 = w1 * x1;
            if (HAS_MU) {
                float w2 = (float)A2[0] + (float)A2[1];
                half2v h45 = __builtin_bit_cast(half2v, g2);
                float x2 = (float)h23[0];
                float xw2 = w2 * x2;
                am0 += xw1 * g.x + xw2 * (float)h23[1];
                am1 += xw1 * g.y + xw2 * (float)h45[0];
                am2 += xw1 * g.z + xw2 * (float)h45[1];
            } else {
                am0 = fmaf(xw1, g.x, am0);
                am1 = fmaf(xw1, g.y, am1);
                am2 = fmaf(xw1, g.z, am2);
            }
        }
    }
#undef LD_IDX

    q[(size_t)n * FD + f] += accq;
    size_t b = (size_t)n * 384;
    float m0 = (HAS_MU ? mup[b + f] : 0.f) + am0;
    float m1 = (HAS_MU ? mup[b + 128 + f] : 0.f) + am1;
    float m2 = (HAS_MU ? mup[b + 256 + f] : 0.f) + am2;
    mun[b + f] = m0; mun[b + 128 + f] = m1; mun[b + 256 + f] = m2;
    mu16n[b + f] = (h16)m0; mu16n[b + 128 + f] = (h16)m1; mu16n[b + 256 + f] = (h16)m2;
}

// ====== fused mixing (+ optional next-iteration interaction MLP) ======
__global__ __launch_bounds__(256) void mixint_kernel(
    const h16* __restrict__ mu16n, const h16* __restrict__ WmuT,
    const h16* __restrict__ W1t, const float* __restrict__ b1,
    const h16* __restrict__ W2t, const float* __restrict__ b2,
    float* __restrict__ q, float* __restrict__ mu, h16* __restrict__ xmw,
    const h16* __restrict__ nW1t, const float* __restrict__ nb1,
    const h16* __restrict__ nW2t, const float* __restrict__ nb2)
{
    __shared__ __align__(16) h16 MM[48 * 264];   // reused as XMP in nW branch
    __shared__ h16 CT[16 * 264];
    __shared__ h16 Hs[16 * 136];
    __shared__ h16 XM[16 * 392];
    const int tid = threadIdx.x;
    const int wave = tid >> 6, lane = tid & 63;
    const int ar = lane & 15, kg = lane >> 4;
    const size_t row0 = (size_t)blockIdx.x * 16;

    {
        f32x4 acc[3][4] = {};
        int aloc[3], dloc[3];
#pragma unroll
        for (int rt = 0; rt < 3; ++rt) {
            int rr = rt * 16 + ar;
            aloc[rt] = rr / 3;
            dloc[rt] = rr - 3 * aloc[rt];
        }
        for (int ks = 0; ks < 128; ks += 32) {
            int k = ks + kg * 8;
            half8 afr[3];
#pragma unroll
            for (int rt = 0; rt < 3; ++rt)
                afr[rt] = *(const half8*)&mu16n[(row0 + aloc[rt]) * 384 + dloc[rt] * 128 + k];
#pragma unroll
            for (int ct = 0; ct < 4; ++ct) {
                int cc = wave * 4 + ct;
                half8 bf = *(const half8*)&WmuT[(size_t)(cc * 16 + ar) * 128 + k];
#pragma unroll
                for (int rt = 0; rt < 3; ++rt)
                    acc[rt][ct] = __builtin_amdgcn_mfma_f32_16x16x32_f16(afr[rt], bf, acc[rt][ct], 0, 0, 0);
            }
        }
#pragma unroll
        for (int rt = 0; rt < 3; ++rt)
#pragma unroll
            for (int ct = 0; ct < 4; ++ct) {
                int col = (wave * 4 + ct) * 16 + ar;
#pragma unroll
                for (int r = 0; r < 4; ++r)
                    MM[(rt * 16 + kg * 4 + r) * 264 + col] = (h16)acc[rt][ct][r];
            }
    }
    __syncthreads();

    float qv[8];   // carried in registers to the epilogue (same (a,ff) mapping)
    {
        int a = tid >> 4, fi = (tid & 15) * 8;
        const float* qp = q + (row0 + a) * 128 + fi;
        float4 q0 = *(const float4*)qp;
        float4 q1 = *(const float4*)(qp + 4);
        qv[0] = q0.x; qv[1] = q0.y; qv[2] = q0.z; qv[3] = q0.w;
        qv[4] = q1.x; qv[5] = q1.y; qv[6] = q1.z; qv[7] = q1.w;
#pragma unroll
        for (int jj = 0; jj < 8; ++jj) {
            int ff = fi + jj;
            float v0 = (float)MM[(a * 3 + 0) * 264 + ff];
            float v1 = (float)MM[(a * 3 + 1) * 264 + ff];
            float v2 = (float)MM[(a * 3 + 2) * 264 + ff];
            CT[a * 264 + 128 + ff] = (h16)sqrtf(v0 * v0 + v1 * v1 + v2 * v2 + 1e-8f);
            CT[a * 264 + ff] = (h16)qv[jj];
        }
    }
    __syncthreads();

    {
        f32x4 a1[2] = {};
        for (int ks = 0; ks < 256; ks += 32) {
            int k = ks + kg * 8;
            half8 af = *(const half8*)&CT[ar * 264 + k];
#pragma unroll
            for (int tt = 0; tt < 2; ++tt) {
                int t = wave * 2 + tt;
                half8 bf = *(const half8*)&W1t[(size_t)(t * 16 + ar) * 256 + k];
                a1[tt] = __builtin_amdgcn_mfma_f32_16x16x32_f16(af, bf, a1[tt], 0, 0, 0);
            }
        }
#pragma unroll
        for (int tt = 0; tt < 2; ++tt) {
            int col = (wave * 2 + tt) * 16 + ar;
            float bb = b1[col];
#pragma unroll
            for (int r = 0; r < 4; ++r)
                Hs[(kg * 4 + r) * 136 + col] = (h16)silu(a1[tt][r] + bb);
        }
    }
    __syncthreads();

    {
        f32x4 a2[6] = {};
        for (int ks = 0; ks < 128; ks += 32) {
            int k = ks + kg * 8;
            half8 af = *(const half8*)&Hs[ar * 136 + k];
#pragma unroll
            for (int tt = 0; tt < 6; ++tt) {
                int t = wave * 6 + tt;
                half8 bf = *(const half8*)&W2t[(size_t)(t * 16 + ar) * 128 + k];
                a2[tt] = __builtin_amdgcn_mfma_f32_16x16x32_f16(af, bf, a2[tt], 0, 0, 0);
            }
        }
#pragma unroll
        for (int tt = 0; tt < 6; ++tt) {
            int col = (wave * 6 + tt) * 16 + ar;
            float bb = b2[col];
#pragma unroll
            for (int r = 0; r < 4; ++r)
                XM[(kg * 4 + r) * 392 + col] = (h16)(a2[tt][r] + bb);
        }
    }
    __syncthreads();

    h16 mh[24];   // per-thread staged mu16, flushed in nW branch
    {
        int a = tid >> 4, fi = (tid & 15) * 8;
        size_t n = row0 + a;
#pragma unroll
        for (int jj = 0; jj < 8; ++jj) {
            int ff = fi + jj;
            float dq  = (float)XM[a * 392 + ff];
            float dm  = (float)XM[a * 392 + 128 + ff];
            float dqm = (float)XM[a * 392 + 256 + ff];
            float v0 = (float)MM[(a * 3 + 0) * 264 + ff], w0 = (float)MM[(a * 3 + 0) * 264 + 128 + ff];
            float v1 = (float)MM[(a * 3 + 1) * 264 + ff], w1 = (float)MM[(a * 3 + 1) * 264 + 128 + ff];
            float v2 = (float)MM[(a * 3 + 2) * 264 + ff], w2 = (float)MM[(a * 3 + 2) * 264 + 128 + ff];
            float sv = v0 * w0 + v1 * w1 + v2 * w2;
            float qn = qv[jj] + dq + dqm * sv;
            q[n * 128 + ff] = qn;
            CT[a * 264 + ff] = (h16)qn;
            size_t b = n * 384 + ff;
            float m0 = mu[b] + dm * w0;
            float m1 = mu[b + 128] + dm * w1;
            float m2 = mu[b + 256] + dm * w2;
            mu[b] = m0; mu[b + 128] = m1; mu[b + 256] = m2;
            mh[jj * 3 + 0] = (h16)m0; mh[jj * 3 + 1] = (h16)m1; mh[jj * 3 + 2] = (h16)m2;
        }
    }
    if (!nW1t) return;
    __syncthreads();

    {
        f32x4 a1[2] = {};
        for (int ks = 0; ks < 128; ks += 32) {
            int k = ks + kg * 8;
            half8 af = *(const half8*)&CT[ar * 264 + k];
#pragma unroll
            for (int tt = 0; tt < 2; ++tt) {
                int t = wave * 2 + tt;
                half8 bf = *(const half8*)&nW1t[(size_t)(t * 16 + ar) * 128 + k];
                a1[tt] = __builtin_amdgcn_mfma_f32_16x16x32_f16(af, bf, a1[tt], 0, 0, 0);
            }
        }
#pragma unroll
        for (int tt = 0; tt < 2; ++tt) {
            int col = (wave * 2 + tt) * 16 + ar;
            float bb = nb1[col];
#pragma unroll
            for (int r = 0; r < 4; ++r)
                Hs[(kg * 4 + r) * 136 + col] = (h16)silu(a1[tt][r] + bb);
        }
        __syncthreads();
        f32x4 a2[6] = {};
        for (int ks = 0; ks < 128; ks += 32) {
            int k = ks + kg * 8;
            half8 af = *(const half8*)&Hs[ar * 136 + k];
#pragma unroll
            for (int tt = 0; tt < 6; ++tt) {
                int t = wave * 6 + tt;
                half8 bf = *(const half8*)&nW2t[(size_t)(t * 16 + ar) * 128 + k];
                a2[tt] = __builtin_amdgcn_mfma_f32_16x16x32_f16(af, bf, a2[tt], 0, 0, 0);
            }
        }
        h16* XMP = MM;
#pragma unroll
        for (int tt = 0; tt < 6; ++tt) {
            int col = (wave * 6 + tt) * 16 + ar;
            float bb = nb2[col];
            int slot = col >> 7, ff = col & 127;
#pragma unroll
            for (int r = 0; r < 4; ++r)
                XMP[((kg * 4 + r) * 128 + ff) * 6 + slot] = (h16)(a2[tt][r] + bb);
        }
        {
            int a = tid >> 4, fi = (tid & 15) * 8;
#pragma unroll
            for (int jj = 0; jj < 8; ++jj)
#pragma unroll
                for (int s = 0; s < 3; ++s)
                    XMP[(a * 128 + fi + jj) * 6 + 3 + s] = mh[jj * 3 + s];
        }
        __syncthreads();
        {
            const uint4* src = (const uint4*)MM;
            uint4* dst = (uint4*)(xmw + row0 * 768);
#pragma unroll
            for (int i = 0; i < 6; ++i)
                dst[tid + i * 256] = src[tid + i * 256];
        }
    }
}

// ====== launch ======
extern "C" void kernel_launch(void* const* d_in, const int* in_sizes, int n_in,
                              void* d_out, int out_size, void* d_ws, size_t ws_size,
                              hipStream_t stream)
{
    const int*   Z       = (const int*)d_in[0];
    const float* R       = (const float*)d_in[1];
    const int*   idx_i   = (const int*)d_in[2];
    const int*   idx_j   = (const int*)d_in[3];
    const float* offsets = (const float*)d_in[4];
    const float* emb     = (const float*)d_in[5];
    const float* filt_W  = (const float*)d_in[6];
    const float* filt_b  = (const float*)d_in[7];
    const float* int_W1  = (const float*)d_in[8];
    const float* int_b1  = (const float*)d_in[9];
    const float* int_W2  = (const float*)d_in[10];
    const float* int_b2  = (const float*)d_in[11];
    const float* mix_Wmu = (const float*)d_in[12];
    const float* mix_W1  = (const float*)d_in[13];
    const float* mix_b1  = (const float*)d_in[14];
    const float* mix_W2  = (const float*)d_in[15];
    const float* mix_b2  = (const float*)d_in[16];

    float* q_out  = (float*)d_out;
    float* mu_out = (float*)d_out + (size_t)NA * FD;

    char* base = (char*)d_ws;
    size_t o = 0;
    auto alloc = [&](size_t bytes) -> void* {
        void* p = base + o;
        o += (bytes + 255) & ~(size_t)255;
        return p;
    };
    h16*   ed     = (h16*)alloc((size_t)NE * 32 * 2);        // merged ph+dir, 64B/edge
    unsigned short* zs = (unsigned short*)alloc((size_t)NE * 2);  // Z[idx_j[e]] stream
    h16*   xm     = (h16*)alloc((size_t)NA * 128 * 6 * 2);   // packed x+mu for edge gather
    h16*   x01z   = (h16*)alloc((size_t)101 * 128 * 2 * 2);  // per-Z (x0,x1) table, 51.7KB
    h16*   mu16p  = (h16*)alloc((size_t)NA * 384 * 2);       // planar pre-mix mu
    float* mu_ws  = (float*)alloc((size_t)NA * 384 * 4);
    h16*   W1t    = (h16*)alloc((size_t)3 * 128 * 128 * 2);
    h16*   W2t    = (h16*)alloc((size_t)3 * 384 * 128 * 2);
    h16*   WmuT   = (h16*)alloc((size_t)3 * 256 * 128 * 2);
    h16*   mW1t   = (h16*)alloc((size_t)3 * 128 * 256 * 2);
    h16*   mW2t   = (h16*)alloc((size_t)3 * 384 * 128 * 2);
    h16*   fwt    = (h16*)alloc((size_t)384 * 32 * 2);
    int*   row_st = (int*)alloc((size_t)(NA + 1) * 4);

    setup_kernel<<<3802, 256, 0, stream>>>(R, idx_i, idx_j, offsets, Z, emb, q_out,
                                           ed, zs, row_st,
                                           int_W1, int_W2, mix_Wmu, mix_W1, mix_W2,
                                           W1t, W2t, WmuT, mW1t, mW2t,
                                           filt_W, filt_b, fwt);

    // iteration 0
    intmlp0z_kernel<<<7, 256, 0, stream>>>(emb, W1t, int_b1, W2t, int_b2, x01z);
    edge_kernel<false><<<NA, 128, 0, stream>>>(ed, fwt, row_st, idx_j, zs,
                                               x01z, nullptr, mu_out, mu16p, q_out);
    mixint_kernel<<<NA / 16, 256, 0, stream>>>(
        mu16p, WmuT, mW1t, mix_b1, mW2t, mix_b2, q_out, mu_out, xm,
        W1t + 16384, int_b1 + 128, W2t + 49152, int_b2 + 384);

    // iteration 1
    edge_kernel<true><<<NA, 128, 0, stream>>>(ed, fwt, row_st, idx_j, zs,
                                              xm, mu_out, mu_ws, mu16p, q_out);
    mixint_kernel<<<NA / 16, 256, 0, stream>>>(
        mu16p, WmuT + 32768, mW1t + 32768, mix_b1 + 128, mW2t + 49152, mix_b2 + 384,
        q_out, mu_ws, xm,
        W1t + 32768, int_b1 + 256, W2t + 98304, int_b2 + 768);

    // iteration 2
    edge_kernel<true><<<NA, 128, 0, stream>>>(ed, fwt, row_st, idx_j, zs,
                                              xm, mu_ws, mu_out, mu16p, q_out);
    mixint_kernel<<<NA / 16, 256, 0, stream>>>(
        mu16p, WmuT + 65536, mW1t + 65536, mix_b1 + 256, mW2t + 98304, mix_b2 + 768,
        q_out, mu_out, xm,
        nullptr, nullptr, nullptr, nullptr);
}

// Round 10
// 421.943 us; speedup vs baseline: 1.0216x; 1.0216x over previous
//
#include <hip/hip_runtime.h>
#include <math.h>

#define NA 10000
#define NE 250000
#define FD 128
#define NRBF 20
#define RCUT 5.0f

typedef _Float16 h16;
typedef __attribute__((ext_vector_type(8))) _Float16 half8;
typedef __attribute__((ext_vector_type(2))) _Float16 half2v;
typedef __attribute__((ext_vector_type(4))) float f32x4;

static __device__ __forceinline__ half8 f32x8_to_h8(const float* p) {
    float4 a = *(const float4*)p;
    float4 b = *(const float4*)(p + 4);
    half8 r;
    r[0] = (h16)a.x; r[1] = (h16)a.y; r[2] = (h16)a.z; r[3] = (h16)a.w;
    r[4] = (h16)b.x; r[5] = (h16)b.y; r[6] = (h16)b.z; r[7] = (h16)b.w;
    return r;
}
static __device__ __forceinline__ float silu(float v) {
    return v / (1.f + expf(-v));
}

// ====== mega setup: geom | csr | weights | q-init (r8 verbatim) ======
// ed[e] = 64B row: 20 gauss*fcut, fcut, 0, Zj-bits, 0 (h16) + float4 dir.
// Element 22 carries (ushort)Z[idx_j[e]] (dot loop reads 0..21 only).
__global__ __launch_bounds__(256) void setup_kernel(
    const float* __restrict__ R, const int* __restrict__ idx_i,
    const int* __restrict__ idx_j, const float* __restrict__ offsets,
    const int* __restrict__ Zt, const float* __restrict__ emb, float* __restrict__ q,
    h16* __restrict__ ed, int* __restrict__ row_start,
    const float* __restrict__ int_W1, const float* __restrict__ int_W2,
    const float* __restrict__ mix_Wmu, const float* __restrict__ mix_W1,
    const float* __restrict__ mix_W2,
    h16* __restrict__ W1t, h16* __restrict__ W2t, h16* __restrict__ WmuT,
    h16* __restrict__ mW1t, h16* __restrict__ mW2t,
    const float* __restrict__ filt_W, const float* __restrict__ filt_b,
    h16* __restrict__ fwt)
{
    const int b = blockIdx.x;
    if (b < 977) {
        int e = b * 256 + threadIdx.x;
        if (e >= NE) return;
        int i = idx_i[e], j = idx_j[e];
        float rx = R[j * 3 + 0] - R[i * 3 + 0] + offsets[e * 3 + 0];
        float ry = R[j * 3 + 1] - R[i * 3 + 1] + offsets[e * 3 + 1];
        float rz = R[j * 3 + 2] - R[i * 3 + 2] + offsets[e * 3 + 2];
        float d = sqrtf(rx * rx + ry * ry + rz * rz);
        float inv = 1.f / d;
        float fcut = 0.f;
        if (d < RCUT) fcut = 0.5f * (cosf(d * (3.14159265358979323846f / RCUT)) + 1.f);
        h16* pp = ed + (size_t)e * 32;
        const float delta = RCUT / 19.f;
        const float coeff = -0.5f / (delta * delta);
#pragma unroll
        for (int r = 0; r < NRBF; ++r) {
            float dc = d - (float)r * delta;
            pp[r] = (h16)(expf(coeff * dc * dc) * fcut);
        }
        pp[20] = (h16)fcut;
        pp[21] = (h16)0.f;
        pp[22] = __builtin_bit_cast(h16, (unsigned short)Zt[j]);
        pp[23] = (h16)0.f;
        *(float4*)(pp + 24) = make_float4(rx * inv, ry * inv, rz * inv, 0.f);
    } else if (b < 1017) {
        int n = (b - 977) * 256 + threadIdx.x;
        if (n > NA) return;
        int lo = 0, hi = NE;
        while (lo < hi) {
            int mid = (lo + hi) >> 1;
            if (idx_i[mid] < n) lo = mid + 1; else hi = mid;
        }
        row_start[n] = lo;
    } else if (b < 3177) {
        int idx = (b - 1017) * 256 + threadIdx.x;
        if (idx < 49152) {                       // int_W1: K=128,N=128
            int bt = idx >> 14, rem = idx & 16383;
            int nn = rem >> 7, kk = rem & 127;
            W1t[idx] = (h16)int_W1[(size_t)bt * 16384 + kk * 128 + nn];
        } else if ((idx -= 49152) < 147456) {    // int_W2: K=128,N=384
            int bt = idx / 49152, rem = idx - bt * 49152;
            int nn = rem >> 7, kk = rem & 127;
            W2t[idx] = (h16)int_W2[(size_t)bt * 49152 + kk * 384 + nn];
        } else if ((idx -= 147456) < 98304) {    // mix_Wmu: K=128,N=256
            int bt = idx >> 15, rem = idx & 32767;
            int nn = rem >> 7, kk = rem & 127;
            WmuT[idx] = (h16)mix_Wmu[(size_t)bt * 32768 + kk * 256 + nn];
        } else if ((idx -= 98304) < 98304) {     // mix_W1: K=256,N=128
            int bt = idx >> 15, rem = idx & 32767;
            int nn = rem >> 8, kk = rem & 255;
            mW1t[idx] = (h16)mix_W1[(size_t)bt * 32768 + kk * 128 + nn];
        } else if ((idx -= 98304) < 147456) {    // mix_W2: K=128,N=384
            int bt = idx / 49152, rem = idx - bt * 49152;
            int nn = rem >> 7, kk = rem & 127;
            mW2t[idx] = (h16)mix_W2[(size_t)bt * 49152 + kk * 384 + nn];
        } else if ((idx -= 147456) < 12288) {    // fwt [384][32]
            int nn = idx >> 5, kk = idx & 31;
            float v = 0.f;
            if (kk < 20) v = filt_W[kk * 384 + nn];
            else if (kk == 20) v = filt_b[nn];
            fwt[idx] = (h16)v;
        }
    } else {
        // q-init: q[n] = emb[Z[n]]
        int a = (b - 3177) * 16 + (threadIdx.x >> 4);
        int f0 = (threadIdx.x & 15) * 8;
        if (a < NA) {
            const float* src = emb + (size_t)Zt[a] * 128 + f0;
            float4 v0 = *(const float4*)src;
            float4 v1 = *(const float4*)(src + 4);
            *(float4*)&q[(size_t)a * 128 + f0] = v0;
            *(float4*)&q[(size_t)a * 128 + f0 + 4] = v1;
        }
    }
}

// ====== iteration-0 interaction MLP, Z-DEDUPED (r8 verbatim) ======
__global__ __launch_bounds__(256) void intmlp0z_kernel(
    const float* __restrict__ emb,
    const h16* __restrict__ W1t, const float* __restrict__ b1,
    const h16* __restrict__ W2t, const float* __restrict__ b2, h16* __restrict__ x01z)
{
    __shared__ h16 Hs[16 * 136];
    const int tid = threadIdx.x;
    const int wave = tid >> 6, lane = tid & 63;
    const int ar = lane & 15, kg = lane >> 4;
    const int row0 = blockIdx.x * 16;

    const int zr = min(row0 + ar, 100);
    f32x4 a1[2] = {};
    for (int ks = 0; ks < 128; ks += 32) {
        int k = ks + kg * 8;
        half8 af = f32x8_to_h8(emb + (size_t)zr * 128 + k);
#pragma unroll
        for (int tt = 0; tt < 2; ++tt) {
            int t = wave * 2 + tt;
            half8 bf = *(const half8*)&W1t[(size_t)(t * 16 + ar) * 128 + k];
            a1[tt] = __builtin_amdgcn_mfma_f32_16x16x32_f16(af, bf, a1[tt], 0, 0, 0);
        }
    }
#pragma unroll
    for (int tt = 0; tt < 2; ++tt) {
        int col = (wave * 2 + tt) * 16 + ar;
        float bb = b1[col];
#pragma unroll
        for (int r = 0; r < 4; ++r)
            Hs[(kg * 4 + r) * 136 + col] = (h16)silu(a1[tt][r] + bb);
    }
    __syncthreads();
    f32x4 a2[6] = {};
    for (int ks = 0; ks < 128; ks += 32) {
        int k = ks + kg * 8;
        half8 af = *(const half8*)&Hs[ar * 136 + k];
#pragma unroll
        for (int tt = 0; tt < 6; ++tt) {
            int t = wave * 6 + tt;
            half8 bf = *(const half8*)&W2t[(size_t)(t * 16 + ar) * 128 + k];
            a2[tt] = __builtin_amdgcn_mfma_f32_16x16x32_f16(af, bf, a2[tt], 0, 0, 0);
        }
    }
#pragma unroll
    for (int tt = 0; tt < 6; ++tt) {
        int col = (wave * 6 + tt) * 16 + ar;
        if (col < 256) {
            float bb = b2[col];
            int slot = col >> 7, ff = col & 127;
#pragma unroll
            for (int r = 0; r < 4; ++r) {
                int z = row0 + kg * 4 + r;
                if (z <= 100)
                    x01z[((size_t)z * 128 + ff) * 2 + slot] = (h16)(a2[tt][r] + bb);
            }
        }
    }
}

// ====== edge kernel (r8 verbatim — the 418µs control; do not touch) ======
template<bool HAS_MU>
__global__ __launch_bounds__(128, 4) void edge_kernel(
    const h16* __restrict__ ed, const h16* __restrict__ fwt,
    const int* __restrict__ row_start, const int* __restrict__ idx_j,
    const h16* __restrict__ gat, const float* __restrict__ mup,
    float* __restrict__ mun, h16* __restrict__ mu16n, float* __restrict__ q)
{
    const int n = blockIdx.x, f = threadIdx.x;
    half8 FA[3], FB[3], FC[3];
    {
        const half8* pa = (const half8*)(fwt + (size_t)f * 32);
        const half8* pb = (const half8*)(fwt + (size_t)(128 + f) * 32);
#pragma unroll
        for (int r = 0; r < 3; ++r) { FA[r] = pa[r]; FB[r] = pb[r]; }
        if (HAS_MU) {
            const half8* pc = (const half8*)(fwt + (size_t)(256 + f) * 32);
#pragma unroll
            for (int r = 0; r < 3; ++r) FC[r] = pc[r];
        }
    }
    asm volatile("" : "+v"(FA[0]), "+v"(FA[1]), "+v"(FA[2]),
                      "+v"(FB[0]), "+v"(FB[1]), "+v"(FB[2]));
    if (HAS_MU)
        asm volatile("" : "+v"(FC[0]), "+v"(FC[1]), "+v"(FC[2]));

    half2v fa[12], fb[12], fc[12];
    *(half8*)&fa[0] = FA[0]; *(half8*)&fa[4] = FA[1]; *(half8*)&fa[8] = FA[2];
    *(half8*)&fb[0] = FB[0]; *(half8*)&fb[4] = FB[1]; *(half8*)&fb[8] = FB[2];
    if (HAS_MU) {
        *(half8*)&fc[0] = FC[0]; *(half8*)&fc[4] = FC[1]; *(half8*)&fc[8] = FC[2];
    }

    float accq = 0.f, am0 = 0.f, am1 = 0.f, am2 = 0.f;
    const int e0 = row_start[n], e1 = row_start[n + 1];

    if (HAS_MU) {
        const h16* xmf = gat + (size_t)f * 6;
        if (e0 < e1) {
            int j = idx_j[e0];
            const unsigned* gp = (const unsigned*)(xmf + (size_t)j * 768);
            unsigned g0n = gp[0], g1n = gp[1], g2n = gp[2];
            const h16* pb8 = ed + (size_t)e0 * 32;
            half8 p0n = *(const half8*)pb8;
            half8 p1n = *(const half8*)(pb8 + 8);
            half8 p2n = *(const half8*)(pb8 + 16);
            float4 dn = *(const float4*)(pb8 + 24);
            for (int e = e0; e < e1; ++e) {
                unsigned g0 = g0n, g1 = g1n, g2 = g2n;
                half8 p0 = p0n, p1 = p1n, p2 = p2n;
                float4 g = dn;
                int ep = (e + 1 < e1) ? e + 1 : e;
                int j2 = idx_j[ep];
                const unsigned* gp2 = (const unsigned*)(xmf + (size_t)j2 * 768);
                g0n = gp2[0]; g1n = gp2[1]; g2n = gp2[2];
                const h16* pb2 = ed + (size_t)ep * 32;
                p0n = *(const half8*)pb2;
                p1n = *(const half8*)(pb2 + 8);
                p2n = *(const half8*)(pb2 + 16);
                dn = *(const float4*)(pb2 + 24);
                half2v pr[12];
                *(half8*)&pr[0] = p0; *(half8*)&pr[4] = p1; *(half8*)&pr[8] = p2;
                half2v A0 = {(h16)0.f, (h16)0.f}, A1 = A0, A2 = A0;
#pragma unroll
                for (int r = 0; r < 11; ++r) {
                    A0 = pr[r] * fa[r] + A0;
                    A1 = pr[r] * fb[r] + A1;
                    A2 = pr[r] * fc[r] + A2;
                }
                float w0 = (float)A0[0] + (float)A0[1];
                float w1 = (float)A1[0] + (float)A1[1];
                float w2 = (float)A2[0] + (float)A2[1];
                half2v h01 = __builtin_bit_cast(half2v, g0);
                half2v h23 = __builtin_bit_cast(half2v, g1);
                half2v h45 = __builtin_bit_cast(half2v, g2);
                float x0 = (float)h01[0], x1 = (float)h01[1];
                accq = fmaf(w0, x0, accq);
                float xw1 = w1 * x1;
                float x2 = (float)h23[0];
                float xw2 = w2 * x2;
                am0 += xw1 * g.x + xw2 * (float)h23[1];
                am1 += xw1 * g.y + xw2 * (float)h45[0];
                am2 += xw1 * g.z + xw2 * (float)h45[1];
            }
        }
    } else {
        const h16* xmf = gat + (size_t)f * 2;
        if (e0 < e1) {
            const h16* pb8 = ed + (size_t)e0 * 32;
            half8 p0n = *(const half8*)pb8;
            half8 p1n = *(const half8*)(pb8 + 8);
            half8 p2n = *(const half8*)(pb8 + 16);
            float4 dn = *(const float4*)(pb8 + 24);
            unsigned short z0 = __builtin_bit_cast(unsigned short, (h16)p2n[6]);
            unsigned g0n = *(const unsigned*)(xmf + (size_t)z0 * 256);
            for (int e = e0; e < e1; ++e) {
                unsigned g0 = g0n;
                half8 p0 = p0n, p1 = p1n, p2 = p2n;
                float4 g = dn;
                int ep = (e + 1 < e1) ? e + 1 : e;
                const h16* pb2 = ed + (size_t)ep * 32;
                p0n = *(const half8*)pb2;
                p1n = *(const half8*)(pb2 + 8);
                p2n = *(const half8*)(pb2 + 16);
                dn = *(const float4*)(pb2 + 24);
                unsigned short z2 = __builtin_bit_cast(unsigned short, (h16)p2n[6]);
                g0n = *(const unsigned*)(xmf + (size_t)z2 * 256);
                half2v pr[12];
                *(half8*)&pr[0] = p0; *(half8*)&pr[4] = p1; *(half8*)&pr[8] = p2;
                half2v A0 = {(h16)0.f, (h16)0.f}, A1 = A0;
#pragma unroll
                for (int r = 0; r < 11; ++r) {
                    A0 = pr[r] * fa[r] + A0;
                    A1 = pr[r] * fb[r] + A1;
                }
                float w0 = (float)A0[0] + (float)A0[1];
                float w1 = (float)A1[0] + (float)A1[1];
                half2v h01 = __builtin_bit_cast(half2v, g0);
                float x0 = (float)h01[0], x1 = (float)h01[1];
                accq = fmaf(w0, x0, accq);
                float xw1 = w1 * x1;
                am0 = fmaf(xw1, g.x, am0);
                am1 = fmaf(xw1, g.y, am1);
                am2 = fmaf(xw1, g.z, am2);
            }
        }
    }

    q[(size_t)n * FD + f] += accq;
    size_t b = (size_t)n * 384;
    float m0 = (HAS_MU ? mup[b + f] : 0.f) + am0;
    float m1 = (HAS_MU ? mup[b + 128 + f] : 0.f) + am1;
    float m2 = (HAS_MU ? mup[b + 256 + f] : 0.f) + am2;
    mun[b + f] = m0; mun[b + 128 + f] = m1; mun[b + 256 + f] = m2;
    mu16n[b + f] = (h16)m0; mu16n[b + 128 + f] = (h16)m1; mu16n[b + 256 + f] = (h16)m2;
}

// ====== fused mixing — 512 threads / 8 waves (was 256/4) ======
// Same grid (625), same LDS (50.6KB), same per-block work. Mixint was
// grid-starved: 625 blocks ≈ 2.44/CU × 4 waves ≈ 10 waves/CU with 5
// internal barriers — latency-bound. 8 waves/block doubles resident waves.
// Column tiles re-spread over 8 waves (ct:4→2, tt:2→1, 6→3); per-atom
// stages go 16thr×8feat → 32thr×4feat. All (thread→data) maps unique.
__global__ __launch_bounds__(512) void mixint_kernel(
    const h16* __restrict__ mu16n, const h16* __restrict__ WmuT,
    const h16* __restrict__ W1t, const float* __restrict__ b1,
    const h16* __restrict__ W2t, const float* __restrict__ b2,
    float* __restrict__ q, float* __restrict__ mu, h16* __restrict__ xmw,
    const h16* __restrict__ nW1t, const float* __restrict__ nb1,
    const h16* __restrict__ nW2t, const float* __restrict__ nb2)
{
    __shared__ __align__(16) h16 MM[48 * 264];   // reused as XMP in nW branch
    __shared__ h16 CT[16 * 264];
    __shared__ h16 Hs[16 * 136];
    __shared__ h16 XM[16 * 392];
    const int tid = threadIdx.x;
    const int wave = tid >> 6, lane = tid & 63;   // wave 0..7
    const int ar = lane & 15, kg = lane >> 4;
    const size_t row0 = (size_t)blockIdx.x * 16;

    {   // Wmu GEMM: [48 x 128] @ [128 x 256]
        f32x4 acc[3][2] = {};
        int aloc[3], dloc[3];
#pragma unroll
        for (int rt = 0; rt < 3; ++rt) {
            int rr = rt * 16 + ar;
            aloc[rt] = rr / 3;
            dloc[rt] = rr - 3 * aloc[rt];
        }
        for (int ks = 0; ks < 128; ks += 32) {
            int k = ks + kg * 8;
            half8 afr[3];
#pragma unroll
            for (int rt = 0; rt < 3; ++rt)
                afr[rt] = *(const half8*)&mu16n[(row0 + aloc[rt]) * 384 + dloc[rt] * 128 + k];
#pragma unroll
            for (int ct = 0; ct < 2; ++ct) {
                int cc = wave * 2 + ct;           // 0..15
                half8 bf = *(const half8*)&WmuT[(size_t)(cc * 16 + ar) * 128 + k];
#pragma unroll
                for (int rt = 0; rt < 3; ++rt)
                    acc[rt][ct] = __builtin_amdgcn_mfma_f32_16x16x32_f16(afr[rt], bf, acc[rt][ct], 0, 0, 0);
            }
        }
#pragma unroll
        for (int rt = 0; rt < 3; ++rt)
#pragma unroll
            for (int ct = 0; ct < 2; ++ct) {
                int col = (wave * 2 + ct) * 16 + ar;
#pragma unroll
                for (int r = 0; r < 4; ++r)
                    MM[(rt * 16 + kg * 4 + r) * 264 + col] = (h16)acc[rt][ct][r];
            }
    }
    __syncthreads();

    float qv[4];   // carried to epilogue (identical (a,fi) mapping there)
    {
        int a = tid >> 5, fi = (tid & 31) * 4;    // 32 threads/atom, 4 feats
        const float* qp = q + (row0 + a) * 128 + fi;
        float4 q0 = *(const float4*)qp;
        qv[0] = q0.x; qv[1] = q0.y; qv[2] = q0.z; qv[3] = q0.w;
#pragma unroll
        for (int jj = 0; jj < 4; ++jj) {
            int ff = fi + jj;
            float v0 = (float)MM[(a * 3 + 0) * 264 + ff];
            float v1 = (float)MM[(a * 3 + 1) * 264 + ff];
            float v2 = (float)MM[(a * 3 + 2) * 264 + ff];
            CT[a * 264 + 128 + ff] = (h16)sqrtf(v0 * v0 + v1 * v1 + v2 * v2 + 1e-8f);
            CT[a * 264 + ff] = (h16)qv[jj];
        }
    }
    __syncthreads();

    {   // W1 GEMM: [16 x 256] @ [256 x 128] — 8 col-tiles, 1/wave
        f32x4 a1 = {};
        for (int ks = 0; ks < 256; ks += 32) {
            int k = ks + kg * 8;
            half8 af = *(const half8*)&CT[ar * 264 + k];
            half8 bf = *(const half8*)&W1t[(size_t)(wave * 16 + ar) * 256 + k];
            a1 = __builtin_amdgcn_mfma_f32_16x16x32_f16(af, bf, a1, 0, 0, 0);
        }
        int col = wave * 16 + ar;
        float bb = b1[col];
#pragma unroll
        for (int r = 0; r < 4; ++r)
            Hs[(kg * 4 + r) * 136 + col] = (h16)silu(a1[r] + bb);
    }
    __syncthreads();

    {   // W2 GEMM: [16 x 128] @ [128 x 384] — 24 col-tiles, 3/wave
        f32x4 a2[3] = {};
        for (int ks = 0; ks < 128; ks += 32) {
            int k = ks + kg * 8;
            half8 af = *(const half8*)&Hs[ar * 136 + k];
#pragma unroll
            for (int tt = 0; tt < 3; ++tt) {
                int t = wave * 3 + tt;
                half8 bf = *(const half8*)&W2t[(size_t)(t * 16 + ar) * 128 + k];
                a2[tt] = __builtin_amdgcn_mfma_f32_16x16x32_f16(af, bf, a2[tt], 0, 0, 0);
            }
        }
#pragma unroll
        for (int tt = 0; tt < 3; ++tt) {
            int col = (wave * 3 + tt) * 16 + ar;
            float bb = b2[col];
#pragma unroll
            for (int r = 0; r < 4; ++r)
                XM[(kg * 4 + r) * 392 + col] = (h16)(a2[tt][r] + bb);
        }
    }
    __syncthreads();

    h16 mh[12];   // per-thread staged mu16 (4 ff x 3 dims)
    {
        int a = tid >> 5, fi = (tid & 31) * 4;
        size_t n = row0 + a;
#pragma unroll
        for (int jj = 0; jj < 4; ++jj) {
            int ff = fi + jj;
            float dq  = (float)XM[a * 392 + ff];
            float dm  = (float)XM[a * 392 + 128 + ff];
            float dqm = (float)XM[a * 392 + 256 + ff];
            float v0 = (float)MM[(a * 3 + 0) * 264 + ff], w0 = (float)MM[(a * 3 + 0) * 264 + 128 + ff];
            float v1 = (float)MM[(a * 3 + 1) * 264 + ff], w1 = (float)MM[(a * 3 + 1) * 264 + 128 + ff];
            float v2 = (float)MM[(a * 3 + 2) * 264 + ff], w2 = (float)MM[(a * 3 + 2) * 264 + 128 + ff];
            float sv = v0 * w0 + v1 * w1 + v2 * w2;
            float qn = qv[jj] + dq + dqm * sv;
            q[n * 128 + ff] = qn;
            CT[a * 264 + ff] = (h16)qn;
            size_t b = n * 384 + ff;
            float m0 = mu[b] + dm * w0;
            float m1 = mu[b + 128] + dm * w1;
            float m2 = mu[b + 256] + dm * w2;
            mu[b] = m0; mu[b + 128] = m1; mu[b + 256] = m2;
            mh[jj * 3 + 0] = (h16)m0; mh[jj * 3 + 1] = (h16)m1; mh[jj * 3 + 2] = (h16)m2;
        }
    }
    if (!nW1t) return;
    __syncthreads();

    {   // next-iter W1: [16 x 128] @ [128 x 128] — 8 col-tiles, 1/wave
        f32x4 a1 = {};
        for (int ks = 0; ks < 128; ks += 32) {
            int k = ks + kg * 8;
            half8 af = *(const half8*)&CT[ar * 264 + k];
            half8 bf = *(const half8*)&nW1t[(size_t)(wave * 16 + ar) * 128 + k];
            a1 = __builtin_amdgcn_mfma_f32_16x16x32_f16(af, bf, a1, 0, 0, 0);
        }
        int col = wave * 16 + ar;
        float bb = nb1[col];
#pragma unroll
        for (int r = 0; r < 4; ++r)
            Hs[(kg * 4 + r) * 136 + col] = (h16)silu(a1[r] + bb);
        __syncthreads();
        // next-iter W2: [16 x 128] @ [128 x 384] — 24 col-tiles, 3/wave
        f32x4 a2[3] = {};
        for (int ks = 0; ks < 128; ks += 32) {
            int k = ks + kg * 8;
            half8 af = *(const half8*)&Hs[ar * 136 + k];
#pragma unroll
            for (int tt = 0; tt < 3; ++tt) {
                int t = wave * 3 + tt;
                half8 bf = *(const half8*)&nW2t[(size_t)(t * 16 + ar) * 128 + k];
                a2[tt] = __builtin_amdgcn_mfma_f32_16x16x32_f16(af, bf, a2[tt], 0, 0, 0);
            }
        }
        h16* XMP = MM;
#pragma unroll
        for (int tt = 0; tt < 3; ++tt) {
            int col = (wave * 3 + tt) * 16 + ar;
            float bb = nb2[col];
            int slot = col >> 7, ff = col & 127;
#pragma unroll
            for (int r = 0; r < 4; ++r)
                XMP[((kg * 4 + r) * 128 + ff) * 6 + slot] = (h16)(a2[tt][r] + bb);
        }
        {
            int a = tid >> 5, fi = (tid & 31) * 4;
#pragma unroll
            for (int jj = 0; jj < 4; ++jj)
#pragma unroll
                for (int s = 0; s < 3; ++s)
                    XMP[(a * 128 + fi + jj) * 6 + 3 + s] = mh[jj * 3 + s];
        }
        __syncthreads();
        {
            // 16 atoms * 768 h16 = 1536 uint4; 512 threads x 3
            const uint4* src = (const uint4*)MM;
            uint4* dst = (uint4*)(xmw + row0 * 768);
#pragma unroll
            for (int i = 0; i < 3; ++i)
                dst[tid + i * 512] = src[tid + i * 512];
        }
    }
}

// ====== launch ======
extern "C" void kernel_launch(void* const* d_in, const int* in_sizes, int n_in,
                              void* d_out, int out_size, void* d_ws, size_t ws_size,
                              hipStream_t stream)
{
    const int*   Z       = (const int*)d_in[0];
    const float* R       = (const float*)d_in[1];
    const int*   idx_i   = (const int*)d_in[2];
    const int*   idx_j   = (const int*)d_in[3];
    const float* offsets = (const float*)d_in[4];
    const float* emb     = (const float*)d_in[5];
    const float* filt_W  = (const float*)d_in[6];
    const float* filt_b  = (const float*)d_in[7];
    const float* int_W1  = (const float*)d_in[8];
    const float* int_b1  = (const float*)d_in[9];
    const float* int_W2  = (const float*)d_in[10];
    const float* int_b2  = (const float*)d_in[11];
    const float* mix_Wmu = (const float*)d_in[12];
    const float* mix_W1  = (const float*)d_in[13];
    const float* mix_b1  = (const float*)d_in[14];
    const float* mix_W2  = (const float*)d_in[15];
    const float* mix_b2  = (const float*)d_in[16];

    float* q_out  = (float*)d_out;
    float* mu_out = (float*)d_out + (size_t)NA * FD;

    char* base = (char*)d_ws;
    size_t o = 0;
    auto alloc = [&](size_t bytes) -> void* {
        void* p = base + o;
        o += (bytes + 255) & ~(size_t)255;
        return p;
    };
    h16*   ed     = (h16*)alloc((size_t)NE * 32 * 2);        // merged ph+zj+dir, 64B/edge
    h16*   xm     = (h16*)alloc((size_t)NA * 128 * 6 * 2);   // packed x+mu for edge gather
    h16*   x01z   = (h16*)alloc((size_t)101 * 128 * 2 * 2);  // per-Z (x0,x1) table, 51.7KB
    h16*   mu16p  = (h16*)alloc((size_t)NA * 384 * 2);       // planar pre-mix mu
    float* mu_ws  = (float*)alloc((size_t)NA * 384 * 4);
    h16*   W1t    = (h16*)alloc((size_t)3 * 128 * 128 * 2);
    h16*   W2t    = (h16*)alloc((size_t)3 * 384 * 128 * 2);
    h16*   WmuT   = (h16*)alloc((size_t)3 * 256 * 128 * 2);
    h16*   mW1t   = (h16*)alloc((size_t)3 * 128 * 256 * 2);
    h16*   mW2t   = (h16*)alloc((size_t)3 * 384 * 128 * 2);
    h16*   fwt    = (h16*)alloc((size_t)384 * 32 * 2);
    int*   row_st = (int*)alloc((size_t)(NA + 1) * 4);

    setup_kernel<<<3802, 256, 0, stream>>>(R, idx_i, idx_j, offsets, Z, emb, q_out,
                                           ed, row_st,
                                           int_W1, int_W2, mix_Wmu, mix_W1, mix_W2,
                                           W1t, W2t, WmuT, mW1t, mW2t,
                                           filt_W, filt_b, fwt);

    // iteration 0
    intmlp0z_kernel<<<7, 256, 0, stream>>>(emb, W1t, int_b1, W2t, int_b2, x01z);
    edge_kernel<false><<<NA, 128, 0, stream>>>(ed, fwt, row_st, idx_j,
                                               x01z, nullptr, mu_out, mu16p, q_out);
    mixint_kernel<<<NA / 16, 512, 0, stream>>>(
        mu16p, WmuT, mW1t, mix_b1, mW2t, mix_b2, q_out, mu_out, xm,
        W1t + 16384, int_b1 + 128, W2t + 49152, int_b2 + 384);

    // iteration 1
    edge_kernel<true><<<NA, 128, 0, stream>>>(ed, fwt, row_st, idx_j,
                                              xm, mu_out, mu_ws, mu16p, q_out);
    mixint_kernel<<<NA / 16, 512, 0, stream>>>(
        mu16p, WmuT + 32768, mW1t + 32768, mix_b1 + 128, mW2t + 49152, mix_b2 + 384,
        q_out, mu_ws, xm,
        W1t + 32768, int_b1 + 256, W2t + 98304, int_b2 + 768);

    // iteration 2
    edge_kernel<true><<<NA, 128, 0, stream>>>(ed, fwt, row_st, idx_j,
                                              xm, mu_ws, mu_out, mu16p, q_out);
    mixint_kernel<<<NA / 16, 512, 0, stream>>>(
        mu16p, WmuT + 65536, mW1t + 65536, mix_b1 + 256, mW2t + 98304, mix_b2 + 768,
        q_out, mu_out, xm,
        nullptr, nullptr, nullptr, nullptr);
}

// Round 11
// 419.797 us; speedup vs baseline: 1.0268x; 1.0051x over previous
//
#include <hip/hip_runtime.h>
#include <math.h>

#define NA 10000
#define NE 250000
#define FD 128
#define NRBF 20
#define RCUT 5.0f

typedef _Float16 h16;
typedef __attribute__((ext_vector_type(8))) _Float16 half8;
typedef __attribute__((ext_vector_type(2))) _Float16 half2v;
typedef __attribute__((ext_vector_type(4))) float f32x4;

static __device__ __forceinline__ half8 f32x8_to_h8(const float* p) {
    float4 a = *(const float4*)p;
    float4 b = *(const float4*)(p + 4);
    half8 r;
    r[0] = (h16)a.x; r[1] = (h16)a.y; r[2] = (h16)a.z; r[3] = (h16)a.w;
    r[4] = (h16)b.x; r[5] = (h16)b.y; r[6] = (h16)b.z; r[7] = (h16)b.w;
    return r;
}
static __device__ __forceinline__ float silu(float v) {
    return v / (1.f + expf(-v));
}

// ====== mega setup: geom | csr | weights | q-init (r8 verbatim) ======
// ed[e] = 64B row: 20 gauss*fcut, fcut, 0, Zj-bits, 0 (h16) + float4 dir.
// Element 22 carries (ushort)Z[idx_j[e]] (dot loop reads 0..21 only).
__global__ __launch_bounds__(256) void setup_kernel(
    const float* __restrict__ R, const int* __restrict__ idx_i,
    const int* __restrict__ idx_j, const float* __restrict__ offsets,
    const int* __restrict__ Zt, const float* __restrict__ emb, float* __restrict__ q,
    h16* __restrict__ ed, int* __restrict__ row_start,
    const float* __restrict__ int_W1, const float* __restrict__ int_W2,
    const float* __restrict__ mix_Wmu, const float* __restrict__ mix_W1,
    const float* __restrict__ mix_W2,
    h16* __restrict__ W1t, h16* __restrict__ W2t, h16* __restrict__ WmuT,
    h16* __restrict__ mW1t, h16* __restrict__ mW2t,
    const float* __restrict__ filt_W, const float* __restrict__ filt_b,
    h16* __restrict__ fwt)
{
    const int b = blockIdx.x;
    if (b < 977) {
        int e = b * 256 + threadIdx.x;
        if (e >= NE) return;
        int i = idx_i[e], j = idx_j[e];
        float rx = R[j * 3 + 0] - R[i * 3 + 0] + offsets[e * 3 + 0];
        float ry = R[j * 3 + 1] - R[i * 3 + 1] + offsets[e * 3 + 1];
        float rz = R[j * 3 + 2] - R[i * 3 + 2] + offsets[e * 3 + 2];
        float d = sqrtf(rx * rx + ry * ry + rz * rz);
        float inv = 1.f / d;
        float fcut = 0.f;
        if (d < RCUT) fcut = 0.5f * (cosf(d * (3.14159265358979323846f / RCUT)) + 1.f);
        h16* pp = ed + (size_t)e * 32;
        const float delta = RCUT / 19.f;
        const float coeff = -0.5f / (delta * delta);
#pragma unroll
        for (int r = 0; r < NRBF; ++r) {
            float dc = d - (float)r * delta;
            pp[r] = (h16)(expf(coeff * dc * dc) * fcut);
        }
        pp[20] = (h16)fcut;
        pp[21] = (h16)0.f;
        pp[22] = __builtin_bit_cast(h16, (unsigned short)Zt[j]);
        pp[23] = (h16)0.f;
        *(float4*)(pp + 24) = make_float4(rx * inv, ry * inv, rz * inv, 0.f);
    } else if (b < 1017) {
        int n = (b - 977) * 256 + threadIdx.x;
        if (n > NA) return;
        int lo = 0, hi = NE;
        while (lo < hi) {
            int mid = (lo + hi) >> 1;
            if (idx_i[mid] < n) lo = mid + 1; else hi = mid;
        }
        row_start[n] = lo;
    } else if (b < 3177) {
        int idx = (b - 1017) * 256 + threadIdx.x;
        if (idx < 49152) {                       // int_W1: K=128,N=128
            int bt = idx >> 14, rem = idx & 16383;
            int nn = rem >> 7, kk = rem & 127;
            W1t[idx] = (h16)int_W1[(size_t)bt * 16384 + kk * 128 + nn];
        } else if ((idx -= 49152) < 147456) {    // int_W2: K=128,N=384
            int bt = idx / 49152, rem = idx - bt * 49152;
            int nn = rem >> 7, kk = rem & 127;
            W2t[idx] = (h16)int_W2[(size_t)bt * 49152 + kk * 384 + nn];
        } else if ((idx -= 147456) < 98304) {    // mix_Wmu: K=128,N=256
            int bt = idx >> 15, rem = idx & 32767;
            int nn = rem >> 7, kk = rem & 127;
            WmuT[idx] = (h16)mix_Wmu[(size_t)bt * 32768 + kk * 256 + nn];
        } else if ((idx -= 98304) < 98304) {     // mix_W1: K=256,N=128
            int bt = idx >> 15, rem = idx & 32767;
            int nn = rem >> 8, kk = rem & 255;
            mW1t[idx] = (h16)mix_W1[(size_t)bt * 32768 + kk * 128 + nn];
        } else if ((idx -= 98304) < 147456) {    // mix_W2: K=128,N=384
            int bt = idx / 49152, rem = idx - bt * 49152;
            int nn = rem >> 7, kk = rem & 127;
            mW2t[idx] = (h16)mix_W2[(size_t)bt * 49152 + kk * 384 + nn];
        } else if ((idx -= 147456) < 12288) {    // fwt [384][32]
            int nn = idx >> 5, kk = idx & 31;
            float v = 0.f;
            if (kk < 20) v = filt_W[kk * 384 + nn];
            else if (kk == 20) v = filt_b[nn];
            fwt[idx] = (h16)v;
        }
    } else {
        // q-init: q[n] = emb[Z[n]]
        int a = (b - 3177) * 16 + (threadIdx.x >> 4);
        int f0 = (threadIdx.x & 15) * 8;
        if (a < NA) {
            const float* src = emb + (size_t)Zt[a] * 128 + f0;
            float4 v0 = *(const float4*)src;
            float4 v1 = *(const float4*)(src + 4);
            *(float4*)&q[(size_t)a * 128 + f0] = v0;
            *(float4*)&q[(size_t)a * 128 + f0 + 4] = v1;
        }
    }
}

// ====== iteration-0 interaction MLP, Z-DEDUPED (r8 verbatim) ======
__global__ __launch_bounds__(256) void intmlp0z_kernel(
    const float* __restrict__ emb,
    const h16* __restrict__ W1t, const float* __restrict__ b1,
    const h16* __restrict__ W2t, const float* __restrict__ b2, h16* __restrict__ x01z)
{
    __shared__ h16 Hs[16 * 136];
    const int tid = threadIdx.x;
    const int wave = tid >> 6, lane = tid & 63;
    const int ar = lane & 15, kg = lane >> 4;
    const int row0 = blockIdx.x * 16;

    const int zr = min(row0 + ar, 100);
    f32x4 a1[2] = {};
    for (int ks = 0; ks < 128; ks += 32) {
        int k = ks + kg * 8;
        half8 af = f32x8_to_h8(emb + (size_t)zr * 128 + k);
#pragma unroll
        for (int tt = 0; tt < 2; ++tt) {
            int t = wave * 2 + tt;
            half8 bf = *(const half8*)&W1t[(size_t)(t * 16 + ar) * 128 + k];
            a1[tt] = __builtin_amdgcn_mfma_f32_16x16x32_f16(af, bf, a1[tt], 0, 0, 0);
        }
    }
#pragma unroll
    for (int tt = 0; tt < 2; ++tt) {
        int col = (wave * 2 + tt) * 16 + ar;
        float bb = b1[col];
#pragma unroll
        for (int r = 0; r < 4; ++r)
            Hs[(kg * 4 + r) * 136 + col] = (h16)silu(a1[tt][r] + bb);
    }
    __syncthreads();
    f32x4 a2[6] = {};
    for (int ks = 0; ks < 128; ks += 32) {
        int k = ks + kg * 8;
        half8 af = *(const half8*)&Hs[ar * 136 + k];
#pragma unroll
        for (int tt = 0; tt < 6; ++tt) {
            int t = wave * 6 + tt;
            half8 bf = *(const half8*)&W2t[(size_t)(t * 16 + ar) * 128 + k];
            a2[tt] = __builtin_amdgcn_mfma_f32_16x16x32_f16(af, bf, a2[tt], 0, 0, 0);
        }
    }
#pragma unroll
    for (int tt = 0; tt < 6; ++tt) {
        int col = (wave * 6 + tt) * 16 + ar;
        if (col < 256) {
            float bb = b2[col];
            int slot = col >> 7, ff = col & 127;
#pragma unroll
            for (int r = 0; r < 4; ++r) {
                int z = row0 + kg * 4 + r;
                if (z <= 100)
                    x01z[((size_t)z * 128 + ff) * 2 + slot] = (h16)(a2[tt][r] + bb);
            }
        }
    }
}

// ====== edge kernel: r8 body + DEPTH-2 gather (HAS_MU only) ======
// VALUBusy 62% = 38% stall; the xm gather is mostly an L3 hit (~400-600cy,
// 15.4MB table >> 4MB per-XCD L2) but was issued only ONE iteration
// (~200-250cy) before use. Depth-2 doubles coverage. This is the clean
// isolation: r6 bundled it with LDS-staging (overhead regressed), r9 tested
// index-prefetch alone (null). Cost: 3 register rotations + 1 ternary/iter.
// Compute body and edge<false> unchanged (control).
template<bool HAS_MU>
__global__ __launch_bounds__(128, 4) void edge_kernel(
    const h16* __restrict__ ed, const h16* __restrict__ fwt,
    const int* __restrict__ row_start, const int* __restrict__ idx_j,
    const h16* __restrict__ gat, const float* __restrict__ mup,
    float* __restrict__ mun, h16* __restrict__ mu16n, float* __restrict__ q)
{
    const int n = blockIdx.x, f = threadIdx.x;
    half8 FA[3], FB[3], FC[3];
    {
        const half8* pa = (const half8*)(fwt + (size_t)f * 32);
        const half8* pb = (const half8*)(fwt + (size_t)(128 + f) * 32);
#pragma unroll
        for (int r = 0; r < 3; ++r) { FA[r] = pa[r]; FB[r] = pb[r]; }
        if (HAS_MU) {
            const half8* pc = (const half8*)(fwt + (size_t)(256 + f) * 32);
#pragma unroll
            for (int r = 0; r < 3; ++r) FC[r] = pc[r];
        }
    }
    asm volatile("" : "+v"(FA[0]), "+v"(FA[1]), "+v"(FA[2]),
                      "+v"(FB[0]), "+v"(FB[1]), "+v"(FB[2]));
    if (HAS_MU)
        asm volatile("" : "+v"(FC[0]), "+v"(FC[1]), "+v"(FC[2]));

    half2v fa[12], fb[12], fc[12];
    *(half8*)&fa[0] = FA[0]; *(half8*)&fa[4] = FA[1]; *(half8*)&fa[8] = FA[2];
    *(half8*)&fb[0] = FB[0]; *(half8*)&fb[4] = FB[1]; *(half8*)&fb[8] = FB[2];
    if (HAS_MU) {
        *(half8*)&fc[0] = FC[0]; *(half8*)&fc[4] = FC[1]; *(half8*)&fc[8] = FC[2];
    }

    float accq = 0.f, am0 = 0.f, am1 = 0.f, am2 = 0.f;
    const int e0 = row_start[n], e1 = row_start[n + 1];

    if (HAS_MU) {
        const h16* xmf = gat + (size_t)f * 6;
        if (e0 < e1) {
            const int elast = e1 - 1;
            // depth-2 prologue: gathers for e0 (A) and e0+1 (B)
            int jA0 = idx_j[e0];
            const unsigned* gpA = (const unsigned*)(xmf + (size_t)jA0 * 768);
            unsigned a0 = gpA[0], a1 = gpA[1], a2 = gpA[2];
            int eB = (e0 + 1 < elast) ? e0 + 1 : elast;
            int jB0 = idx_j[eB];
            const unsigned* gpB = (const unsigned*)(xmf + (size_t)jB0 * 768);
            unsigned b0 = gpB[0], b1 = gpB[1], b2 = gpB[2];
            // ed-row prologue (edge e0)
            const h16* pb8 = ed + (size_t)e0 * 32;
            half8 p0n = *(const half8*)pb8;
            half8 p1n = *(const half8*)(pb8 + 8);
            half8 p2n = *(const half8*)(pb8 + 16);
            float4 dn = *(const float4*)(pb8 + 24);
            for (int e = e0; e < e1; ++e) {
                unsigned g0 = a0, g1 = a1, g2 = a2;
                a0 = b0; a1 = b1; a2 = b2;
                // issue gather for e+2 (clamped; redundant at tail)
                int e2 = (e + 2 < elast) ? e + 2 : elast;
                int j2 = idx_j[e2];
                const unsigned* gp2 = (const unsigned*)(xmf + (size_t)j2 * 768);
                b0 = gp2[0]; b1 = gp2[1]; b2 = gp2[2];
                half8 p0 = p0n, p1 = p1n, p2 = p2n;
                float4 g = dn;
                // ed row for e+1 (depth-1, streams from L2)
                int ep = (e + 1 < e1) ? e + 1 : e;
                const h16* pb2 = ed + (size_t)ep * 32;
                p0n = *(const half8*)pb2;
                p1n = *(const half8*)(pb2 + 8);
                p2n = *(const half8*)(pb2 + 16);
                dn = *(const float4*)(pb2 + 24);
                // ---- compute on current edge (r2 body, do not touch) ----
                half2v pr[12];
                *(half8*)&pr[0] = p0; *(half8*)&pr[4] = p1; *(half8*)&pr[8] = p2;
                half2v A0 = {(h16)0.f, (h16)0.f}, A1 = A0, A2 = A0;
#pragma unroll
                for (int r = 0; r < 11; ++r) {
                    A0 = pr[r] * fa[r] + A0;
                    A1 = pr[r] * fb[r] + A1;
                    A2 = pr[r] * fc[r] + A2;
                }
                float w0 = (float)A0[0] + (float)A0[1];
                float w1 = (float)A1[0] + (float)A1[1];
                float w2 = (float)A2[0] + (float)A2[1];
                half2v h01 = __builtin_bit_cast(half2v, g0);
                half2v h23 = __builtin_bit_cast(half2v, g1);
                half2v h45 = __builtin_bit_cast(half2v, g2);
                float x0 = (float)h01[0], x1 = (float)h01[1];
                accq = fmaf(w0, x0, accq);
                float xw1 = w1 * x1;
                float x2 = (float)h23[0];
                float xw2 = w2 * x2;
                am0 += xw1 * g.x + xw2 * (float)h23[1];
                am1 += xw1 * g.y + xw2 * (float)h45[0];
                am2 += xw1 * g.z + xw2 * (float)h45[1];
            }
        }
    } else {
        const h16* xmf = gat + (size_t)f * 2;
        if (e0 < e1) {
            const h16* pb8 = ed + (size_t)e0 * 32;
            half8 p0n = *(const half8*)pb8;
            half8 p1n = *(const half8*)(pb8 + 8);
            half8 p2n = *(const half8*)(pb8 + 16);
            float4 dn = *(const float4*)(pb8 + 24);
            unsigned short z0 = __builtin_bit_cast(unsigned short, (h16)p2n[6]);
            unsigned g0n = *(const unsigned*)(xmf + (size_t)z0 * 256);
            for (int e = e0; e < e1; ++e) {
                unsigned g0 = g0n;
                half8 p0 = p0n, p1 = p1n, p2 = p2n;
                float4 g = dn;
                int ep = (e + 1 < e1) ? e + 1 : e;
                const h16* pb2 = ed + (size_t)ep * 32;
                p0n = *(const half8*)pb2;
                p1n = *(const half8*)(pb2 + 8);
                p2n = *(const half8*)(pb2 + 16);
                dn = *(const float4*)(pb2 + 24);
                unsigned short z2 = __builtin_bit_cast(unsigned short, (h16)p2n[6]);
                g0n = *(const unsigned*)(xmf + (size_t)z2 * 256);
                half2v pr[12];
                *(half8*)&pr[0] = p0; *(half8*)&pr[4] = p1; *(half8*)&pr[8] = p2;
                half2v A0 = {(h16)0.f, (h16)0.f}, A1 = A0;
#pragma unroll
                for (int r = 0; r < 11; ++r) {
                    A0 = pr[r] * fa[r] + A0;
                    A1 = pr[r] * fb[r] + A1;
                }
                float w0 = (float)A0[0] + (float)A0[1];
                float w1 = (float)A1[0] + (float)A1[1];
                half2v h01 = __builtin_bit_cast(half2v, g0);
                float x0 = (float)h01[0], x1 = (float)h01[1];
                accq = fmaf(w0, x0, accq);
                float xw1 = w1 * x1;
                am0 = fmaf(xw1, g.x, am0);
                am1 = fmaf(xw1, g.y, am1);
                am2 = fmaf(xw1, g.z, am2);
            }
        }
    }

    q[(size_t)n * FD + f] += accq;
    size_t b = (size_t)n * 384;
    float m0 = (HAS_MU ? mup[b + f] : 0.f) + am0;
    float m1 = (HAS_MU ? mup[b + 128 + f] : 0.f) + am1;
    float m2 = (HAS_MU ? mup[b + 256 + f] : 0.f) + am2;
    mun[b + f] = m0; mun[b + 128 + f] = m1; mun[b + 256 + f] = m2;
    mu16n[b + f] = (h16)m0; mu16n[b + 128 + f] = (h16)m1; mu16n[b + 256 + f] = (h16)m2;
}

// ====== fused mixing (r8 256-thread version with q-carry, verbatim) ======
__global__ __launch_bounds__(256) void mixint_kernel(
    const h16* __restrict__ mu16n, const h16* __restrict__ WmuT,
    const h16* __restrict__ W1t, const float* __restrict__ b1,
    const h16* __restrict__ W2t, const float* __restrict__ b2,
    float* __restrict__ q, float* __restrict__ mu, h16* __restrict__ xmw,
    const h16* __restrict__ nW1t, const float* __restrict__ nb1,
    const h16* __restrict__ nW2t, const float* __restrict__ nb2)
{
    __shared__ __align__(16) h16 MM[48 * 264];   // reused as XMP in nW branch
    __shared__ h16 CT[16 * 264];
    __shared__ h16 Hs[16 * 136];
    __shared__ h16 XM[16 * 392];
    const int tid = threadIdx.x;
    const int wave = tid >> 6, lane = tid & 63;
    const int ar = lane & 15, kg = lane >> 4;
    const size_t row0 = (size_t)blockIdx.x * 16;

    {
        f32x4 acc[3][4] = {};
        int aloc[3], dloc[3];
#pragma unroll
        for (int rt = 0; rt < 3; ++rt) {
            int rr = rt * 16 + ar;
            aloc[rt] = rr / 3;
            dloc[rt] = rr - 3 * aloc[rt];
        }
        for (int ks = 0; ks < 128; ks += 32) {
            int k = ks + kg * 8;
            half8 afr[3];
#pragma unroll
            for (int rt = 0; rt < 3; ++rt)
                afr[rt] = *(const half8*)&mu16n[(row0 + aloc[rt]) * 384 + dloc[rt] * 128 + k];
#pragma unroll
            for (int ct = 0; ct < 4; ++ct) {
                int cc = wave * 4 + ct;
                half8 bf = *(const half8*)&WmuT[(size_t)(cc * 16 + ar) * 128 + k];
#pragma unroll
                for (int rt = 0; rt < 3; ++rt)
                    acc[rt][ct] = __builtin_amdgcn_mfma_f32_16x16x32_f16(afr[rt], bf, acc[rt][ct], 0, 0, 0);
            }
        }
#pragma unroll
        for (int rt = 0; rt < 3; ++rt)
#pragma unroll
            for (int ct = 0; ct < 4; ++ct) {
                int col = (wave * 4 + ct) * 16 + ar;
#pragma unroll
                for (int r = 0; r < 4; ++r)
                    MM[(rt * 16 + kg * 4 + r) * 264 + col] = (h16)acc[rt][ct][r];
            }
    }
    __syncthreads();

    float qv[8];   // carried in registers to the epilogue (same (a,ff) mapping)
    {
        int a = tid >> 4, fi = (tid & 15) * 8;
        const float* qp = q + (row0 + a) * 128 + fi;
        float4 q0 = *(const float4*)qp;
        float4 q1 = *(const float4*)(qp + 4);
        qv[0] = q0.x; qv[1] = q0.y; qv[2] = q0.z; qv[3] = q0.w;
        qv[4] = q1.x; qv[5] = q1.y; qv[6] = q1.z; qv[7] = q1.w;
#pragma unroll
        for (int jj = 0; jj < 8; ++jj) {
            int ff = fi + jj;
            float v0 = (float)MM[(a * 3 + 0) * 264 + ff];
            float v1 = (float)MM[(a * 3 + 1) * 264 + ff];
            float v2 = (float)MM[(a * 3 + 2) * 264 + ff];
            CT[a * 264 + 128 + ff] = (h16)sqrtf(v0 * v0 + v1 * v1 + v2 * v2 + 1e-8f);
            CT[a * 264 + ff] = (h16)qv[jj];
        }
    }
    __syncthreads();

    {
        f32x4 a1[2] = {};
        for (int ks = 0; ks < 256; ks += 32) {
            int k = ks + kg * 8;
            half8 af = *(const half8*)&CT[ar * 264 + k];
#pragma unroll
            for (int tt = 0; tt < 2; ++tt) {
                int t = wave * 2 + tt;
                half8 bf = *(const half8*)&W1t[(size_t)(t * 16 + ar) * 256 + k];
                a1[tt] = __builtin_amdgcn_mfma_f32_16x16x32_f16(af, bf, a1[tt], 0, 0, 0);
            }
        }
#pragma unroll
        for (int tt = 0; tt < 2; ++tt) {
            int col = (wave * 2 + tt) * 16 + ar;
            float bb = b1[col];
#pragma unroll
            for (int r = 0; r < 4; ++r)
                Hs[(kg * 4 + r) * 136 + col] = (h16)silu(a1[tt][r] + bb);
        }
    }
    __syncthreads();

    {
        f32x4 a2[6] = {};
        for (int ks = 0; ks < 128; ks += 32) {
            int k = ks + kg * 8;
            half8 af = *(const half8*)&Hs[ar * 136 + k];
#pragma unroll
            for (int tt = 0; tt < 6; ++tt) {
                int t = wave * 6 + tt;
                half8 bf = *(const half8*)&W2t[(size_t)(t * 16 + ar) * 128 + k];
                a2[tt] = __builtin_amdgcn_mfma_f32_16x16x32_f16(af, bf, a2[tt], 0, 0, 0);
            }
        }
#pragma unroll
        for (int tt = 0; tt < 6; ++tt) {
            int col = (wave * 6 + tt) * 16 + ar;
            float bb = b2[col];
#pragma unroll
            for (int r = 0; r < 4; ++r)
                XM[(kg * 4 + r) * 392 + col] = (h16)(a2[tt][r] + bb);
        }
    }
    __syncthreads();

    h16 mh[24];   // per-thread staged mu16, flushed in nW branch
    {
        int a = tid >> 4, fi = (tid & 15) * 8;
        size_t n = row0 + a;
#pragma unroll
        for (int jj = 0; jj < 8; ++jj) {
            int ff = fi + jj;
            float dq  = (float)XM[a * 392 + ff];
            float dm  = (float)XM[a * 392 + 128 + ff];
            float dqm = (float)XM[a * 392 + 256 + ff];
            float v0 = (float)MM[(a * 3 + 0) * 264 + ff], w0 = (float)MM[(a * 3 + 0) * 264 + 128 + ff];
            float v1 = (float)MM[(a * 3 + 1) * 264 + ff], w1 = (float)MM[(a * 3 + 1) * 264 + 128 + ff];
            float v2 = (float)MM[(a * 3 + 2) * 264 + ff], w2 = (float)MM[(a * 3 + 2) * 264 + 128 + ff];
            float sv = v0 * w0 + v1 * w1 + v2 * w2;
            float qn = qv[jj] + dq + dqm * sv;
            q[n * 128 + ff] = qn;
            CT[a * 264 + ff] = (h16)qn;
            size_t b = n * 384 + ff;
            float m0 = mu[b] + dm * w0;
            float m1 = mu[b + 128] + dm * w1;
            float m2 = mu[b + 256] + dm * w2;
            mu[b] = m0; mu[b + 128] = m1; mu[b + 256] = m2;
            mh[jj * 3 + 0] = (h16)m0; mh[jj * 3 + 1] = (h16)m1; mh[jj * 3 + 2] = (h16)m2;
        }
    }
    if (!nW1t) return;
    __syncthreads();

    {
        f32x4 a1[2] = {};
        for (int ks = 0; ks < 128; ks += 32) {
            int k = ks + kg * 8;
            half8 af = *(const half8*)&CT[ar * 264 + k];
#pragma unroll
            for (int tt = 0; tt < 2; ++tt) {
                int t = wave * 2 + tt;
                half8 bf = *(const half8*)&nW1t[(size_t)(t * 16 + ar) * 128 + k];
                a1[tt] = __builtin_amdgcn_mfma_f32_16x16x32_f16(af, bf, a1[tt], 0, 0, 0);
            }
        }
#pragma unroll
        for (int tt = 0; tt < 2; ++tt) {
            int col = (wave * 2 + tt) * 16 + ar;
            float bb = nb1[col];
#pragma unroll
            for (int r = 0; r < 4; ++r)
                Hs[(kg * 4 + r) * 136 + col] = (h16)silu(a1[tt][r] + bb);
        }
        __syncthreads();
        f32x4 a2[6] = {};
        for (int ks = 0; ks < 128; ks += 32) {
            int k = ks + kg * 8;
            half8 af = *(const half8*)&Hs[ar * 136 + k];
#pragma unroll
            for (int tt = 0; tt < 6; ++tt) {
                int t = wave * 6 + tt;
                half8 bf = *(const half8*)&nW2t[(size_t)(t * 16 + ar) * 128 + k];
                a2[tt] = __builtin_amdgcn_mfma_f32_16x16x32_f16(af, bf, a2[tt], 0, 0, 0);
            }
        }
        h16* XMP = MM;
#pragma unroll
        for (int tt = 0; tt < 6; ++tt) {
            int col = (wave * 6 + tt) * 16 + ar;
            float bb = nb2[col];
            int slot = col >> 7, ff = col & 127;
#pragma unroll
            for (int r = 0; r < 4; ++r)
                XMP[((kg * 4 + r) * 128 + ff) * 6 + slot] = (h16)(a2[tt][r] + bb);
        }
        {
            int a = tid >> 4, fi = (tid & 15) * 8;
#pragma unroll
            for (int jj = 0; jj < 8; ++jj)
#pragma unroll
                for (int s = 0; s < 3; ++s)
                    XMP[(a * 128 + fi + jj) * 6 + 3 + s] = mh[jj * 3 + s];
        }
        __syncthreads();
        {
            const uint4* src = (const uint4*)MM;
            uint4* dst = (uint4*)(xmw + row0 * 768);
#pragma unroll
            for (int i = 0; i < 6; ++i)
                dst[tid + i * 256] = src[tid + i * 256];
        }
    }
}

// ====== launch ======
extern "C" void kernel_launch(void* const* d_in, const int* in_sizes, int n_in,
                              void* d_out, int out_size, void* d_ws, size_t ws_size,
                              hipStream_t stream)
{
    const int*   Z       = (const int*)d_in[0];
    const float* R       = (const float*)d_in[1];
    const int*   idx_i   = (const int*)d_in[2];
    const int*   idx_j   = (const int*)d_in[3];
    const float* offsets = (const float*)d_in[4];
    const float* emb     = (const float*)d_in[5];
    const float* filt_W  = (const float*)d_in[6];
    const float* filt_b  = (const float*)d_in[7];
    const float* int_W1  = (const float*)d_in[8];
    const float* int_b1  = (const float*)d_in[9];
    const float* int_W2  = (const float*)d_in[10];
    const float* int_b2  = (const float*)d_in[11];
    const float* mix_Wmu = (const float*)d_in[12];
    const float* mix_W1  = (const float*)d_in[13];
    const float* mix_b1  = (const float*)d_in[14];
    const float* mix_W2  = (const float*)d_in[15];
    const float* mix_b2  = (const float*)d_in[16];

    float* q_out  = (float*)d_out;
    float* mu_out = (float*)d_out + (size_t)NA * FD;

    char* base = (char*)d_ws;
    size_t o = 0;
    auto alloc = [&](size_t bytes) -> void* {
        void* p = base + o;
        o += (bytes + 255) & ~(size_t)255;
        return p;
    };
    h16*   ed     = (h16*)alloc((size_t)NE * 32 * 2);        // merged ph+zj+dir, 64B/edge
    h16*   xm     = (h16*)alloc((size_t)NA * 128 * 6 * 2);   // packed x+mu for edge gather
    h16*   x01z   = (h16*)alloc((size_t)101 * 128 * 2 * 2);  // per-Z (x0,x1) table, 51.7KB
    h16*   mu16p  = (h16*)alloc((size_t)NA * 384 * 2);       // planar pre-mix mu
    float* mu_ws  = (float*)alloc((size_t)NA * 384 * 4);
    h16*   W1t    = (h16*)alloc((size_t)3 * 128 * 128 * 2);
    h16*   W2t    = (h16*)alloc((size_t)3 * 384 * 128 * 2);
    h16*   WmuT   = (h16*)alloc((size_t)3 * 256 * 128 * 2);
    h16*   mW1t   = (h16*)alloc((size_t)3 * 128 * 256 * 2);
    h16*   mW2t   = (h16*)alloc((size_t)3 * 384 * 128 * 2);
    h16*   fwt    = (h16*)alloc((size_t)384 * 32 * 2);
    int*   row_st = (int*)alloc((size_t)(NA + 1) * 4);

    setup_kernel<<<3802, 256, 0, stream>>>(R, idx_i, idx_j, offsets, Z, emb, q_out,
                                           ed, row_st,
                                           int_W1, int_W2, mix_Wmu, mix_W1, mix_W2,
                                           W1t, W2t, WmuT, mW1t, mW2t,
                                           filt_W, filt_b, fwt);

    // iteration 0
    intmlp0z_kernel<<<7, 256, 0, stream>>>(emb, W1t, int_b1, W2t, int_b2, x01z);
    edge_kernel<false><<<NA, 128, 0, stream>>>(ed, fwt, row_st, idx_j,
                                               x01z, nullptr, mu_out, mu16p, q_out);
    mixint_kernel<<<NA / 16, 256, 0, stream>>>(
        mu16p, WmuT, mW1t, mix_b1, mW2t, mix_b2, q_out, mu_out, xm,
        W1t + 16384, int_b1 + 128, W2t + 49152, int_b2 + 384);

    // iteration 1
    edge_kernel<true><<<NA, 128, 0, stream>>>(ed, fwt, row_st, idx_j,
                                              xm, mu_out, mu_ws, mu16p, q_out);
    mixint_kernel<<<NA / 16, 256, 0, stream>>>(
        mu16p, WmuT + 32768, mW1t + 32768, mix_b1 + 128, mW2t + 49152, mix_b2 + 384,
        q_out, mu_ws, xm,
        W1t + 32768, int_b1 + 256, W2t + 98304, int_b2 + 768);

    // iteration 2
    edge_kernel<true><<<NA, 128, 0, stream>>>(ed, fwt, row_st, idx_j,
                                              xm, mu_ws, mu_out, mu16p, q_out);
    mixint_kernel<<<NA / 16, 256, 0, stream>>>(
        mu16p, WmuT + 65536, mW1t + 65536, mix_b1 + 256, mW2t + 98304, mix_b2 + 768,
        q_out, mu_out, xm,
        nullptr, nullptr, nullptr, nullptr);
}